// Round 4
// baseline (867.706 us; speedup 1.0000x reference)
//
#include <hip/hip_runtime.h>
#include <math.h>

#define HID    128
#define IN_CH  271
#define SEQ    281
#define NCLS   1854
#define BATCH  256
#define M_TOT  (SEQ * BATCH)          // 71936 = 562 * 128
#define KPAD0  288                    // 271 padded to 9*32
#define KPAD1  128

typedef __attribute__((ext_vector_type(8))) short short8;
typedef __attribute__((ext_vector_type(4))) float floatx4;

__device__ __forceinline__ unsigned short f2bf(float f) {
    union { float f; unsigned u; } v; v.f = f;
    unsigned u = v.u;
    u += 0x7FFF + ((u >> 16) & 1);        // RNE
    return (unsigned short)(u >> 16);
}

__device__ __forceinline__ float fast_sigmoid(float s) {
    return 1.f / (1.f + __expf(-s));
}
__device__ __forceinline__ float fast_tanh(float s) {
    float a = fabsf(s);
    float e = __expf(-2.f * a);
    float t = (1.f - e) / (1.f + e);
    return copysignf(t, s);
}

// ---------------------------------------------------------------------------
// Transpose+convert X: X[b][k][t] fp32 -> Abf[(b*281+t)*288 + k] bf16.
// ---------------------------------------------------------------------------
__global__ __launch_bounds__(256) void xt_kernel(
    const float* __restrict__ X, unsigned short* __restrict__ Abf)
{
    const int tb = blockIdx.x;            // 0..4, t-tile of 64
    const int b  = blockIdx.y;
    const int tid = threadIdx.x;
    const int t0 = tb * 64;
    const float* __restrict__ Xb = X + (size_t)b * (IN_CH * SEQ);

    __shared__ float Xl[32][65];

    for (int kc = 0; kc < KPAD0 / 32; ++kc) {
#pragma unroll
        for (int r = 0; r < 8; ++r) {
            int e = tid + 256 * r;
            int kk = e >> 6, tt = e & 63;
            int k = kc * 32 + kk, t = t0 + tt;
            Xl[kk][tt] = (k < IN_CH && t < SEQ) ? Xb[k * SEQ + t] : 0.f;
        }
        __syncthreads();
        {
            int tt = tid >> 2, part = tid & 3;
            int t = t0 + tt;
            if (t < SEQ) {
                union { unsigned short s[8]; uint4 v; } u;
#pragma unroll
                for (int i = 0; i < 8; ++i) u.s[i] = f2bf(Xl[part * 8 + i][tt]);
                *(uint4*)(Abf + ((size_t)b * SEQ + t) * KPAD0 + kc * 32 + part * 8) = u.v;
            }
        }
        __syncthreads();
    }
}

// ---------------------------------------------------------------------------
// Transpose+convert gate weights to [n][k] bf16 (x-part rows only), k padded.
// grid (6, 32): blockIdx.x = layer*3+gate, blockIdx.y = n-slice of 4.
// ---------------------------------------------------------------------------
__global__ __launch_bounds__(256) void wt_kernel(
    const float* __restrict__ Wr0, const float* __restrict__ Wu0, const float* __restrict__ Wo0,
    const float* __restrict__ Wr1, const float* __restrict__ Wu1, const float* __restrict__ Wo1,
    unsigned short* __restrict__ Wt0, unsigned short* __restrict__ Wt1)
{
    const int blk = blockIdx.x;
    const int layer = blk / 3, g = blk % 3;
    const int tid = threadIdx.x;
    const float* __restrict__ W =
        (layer == 0) ? ((g == 0) ? Wr0 : (g == 1) ? Wu0 : Wo0)
                     : ((g == 0) ? Wr1 : (g == 1) ? Wu1 : Wo1);
    const int Kp   = (layer == 0) ? KPAD0 : KPAD1;
    const int Ksrc = (layer == 0) ? IN_CH : HID;
    unsigned short* __restrict__ out =
        (layer == 0) ? (Wt0 + (size_t)g * HID * KPAD0) : (Wt1 + (size_t)g * HID * KPAD1);

    const int n0 = blockIdx.y * 4;
    for (int n = n0; n < n0 + 4; ++n) {
        for (int k = tid; k < Kp; k += 256) {
            float v = (k < Ksrc) ? W[(size_t)k * HID + n] : 0.f;
            out[(size_t)n * Kp + k] = f2bf(v);
        }
    }
}

// ---------------------------------------------------------------------------
// bf16 MFMA GEMM: XG[m][g*128+n] = sum_k A[m][k]*Wt[g][n][k] + bias_g[n]
// ---------------------------------------------------------------------------
__global__ __launch_bounds__(256) void gemm_xg(
    const unsigned short* __restrict__ A,
    const unsigned short* __restrict__ Wt,
    const float* __restrict__ br, const float* __restrict__ bu, const float* __restrict__ bo,
    float* __restrict__ XG, int Kpad)
{
    const int g = blockIdx.y;
    const float* __restrict__ bias = (g == 0) ? br : (g == 1) ? bu : bo;
    const unsigned short* __restrict__ B = Wt + (size_t)g * HID * Kpad;

    __shared__ unsigned short As[128 * 40];
    __shared__ unsigned short Bs[128 * 40];

    const int tid   = threadIdx.x;
    const int wave  = tid >> 6;
    const int lane  = tid & 63;
    const int l15   = lane & 15;
    const int quad  = lane >> 4;
    const int mhalf = wave >> 1;
    const int nhalf = wave & 1;
    const size_t m0 = (size_t)blockIdx.x * 128;

    floatx4 acc[4][4];
#pragma unroll
    for (int im = 0; im < 4; ++im)
#pragma unroll
        for (int in = 0; in < 4; ++in) acc[im][in] = (floatx4)0.f;

    const int r0 = tid >> 2, p0 = tid & 3;
    const int r1 = (tid + 256) >> 2, p1 = tid & 3;

    const int ksteps = Kpad >> 5;
    for (int kt = 0; kt < ksteps; ++kt) {
        if (kt) __syncthreads();
        const int kb = kt * 32;
        uint4 va0 = *(const uint4*)(A + (m0 + r0) * Kpad + kb + p0 * 8);
        uint4 va1 = *(const uint4*)(A + (m0 + r1) * Kpad + kb + p1 * 8);
        uint4 vb0 = *(const uint4*)(B + (size_t)r0 * Kpad + kb + p0 * 8);
        uint4 vb1 = *(const uint4*)(B + (size_t)r1 * Kpad + kb + p1 * 8);
        *(uint4*)(As + r0 * 40 + p0 * 8) = va0;
        *(uint4*)(As + r1 * 40 + p1 * 8) = va1;
        *(uint4*)(Bs + r0 * 40 + p0 * 8) = vb0;
        *(uint4*)(Bs + r1 * 40 + p1 * 8) = vb1;
        __syncthreads();

        short8 af[4], bf[4];
#pragma unroll
        for (int im = 0; im < 4; ++im)
            af[im] = *(const short8*)(As + (mhalf * 64 + im * 16 + l15) * 40 + quad * 8);
#pragma unroll
        for (int in = 0; in < 4; ++in)
            bf[in] = *(const short8*)(Bs + (nhalf * 64 + in * 16 + l15) * 40 + quad * 8);
#pragma unroll
        for (int im = 0; im < 4; ++im)
#pragma unroll
            for (int in = 0; in < 4; ++in)
                acc[im][in] = __builtin_amdgcn_mfma_f32_16x16x32_bf16(
                    af[im], bf[in], acc[im][in], 0, 0, 0);
    }

    float bv[4];
#pragma unroll
    for (int in = 0; in < 4; ++in) bv[in] = bias[nhalf * 64 + in * 16 + l15];
#pragma unroll
    for (int im = 0; im < 4; ++im) {
#pragma unroll
        for (int v = 0; v < 4; ++v) {
            size_t m = m0 + mhalf * 64 + im * 16 + quad * 4 + v;
            float* row = XG + m * 384 + g * HID;
#pragma unroll
            for (int in = 0; in < 4; ++in)
                row[nhalf * 64 + in * 16 + l15] = acc[im][in][v] + bv[in];
        }
    }
}

// ---------------------------------------------------------------------------
// GRU recurrence. 1024 threads/block (16 waves, 1 block/CU), one block per
// batch element. lane = jj*8+q: 8 j-cols x 8 K-eighths per wave; j = wv*8+jj.
// Per-thread recurrent weights: 3 gates x 16 fp32 = 48 VGPRs, kept resident
// (asm memory clobber forbids rematerialization of the global loads).
// K-reduction = 3x shfl_xor (intra-wave). 2 barriers/step. xg prefetched one
// step ahead. h/rh in bank-staggered LDS: q-chunk base word
// (q*16 + 4*(q>>1)) % 32 gives 8 disjoint bank quads; jj broadcast is free.
// ---------------------------------------------------------------------------
#define PADIDX(k) ((k) + 4 * ((k) >> 5))

template <int LAYER>
__global__ __launch_bounds__(1024, 4) void gru_rec(
    const float* __restrict__ Wr, const float* __restrict__ Wu, const float* __restrict__ Wo,
    const float* __restrict__ XG, unsigned short* __restrict__ H0bf,
    const float* __restrict__ Wfc, const float* __restrict__ bfc,
    float* __restrict__ out)
{
    const int b    = blockIdx.x;
    const int tid  = threadIdx.x;
    const int wv   = tid >> 6;        // 0..15
    const int lane = tid & 63;
    const int jj   = lane >> 3;       // 0..7
    const int q    = lane & 7;        // 0..7
    const int j    = wv * 8 + jj;     // 0..127

    __shared__ float h_pad[144];
    __shared__ float rh_pad[144];
    __shared__ float h_fin[HID];

    // recurrent-part weight rows, held in registers (48 fp32)
    float wr[16], wu[16], wo[16];
    const int kbase = (LAYER == 0 ? IN_CH : HID) + q * 16;
#pragma unroll
    for (int kk = 0; kk < 16; ++kk) {
        wr[kk] = Wr[(kbase + kk) * HID + j];
        wu[kk] = Wu[(kbase + kk) * HID + j];
        wo[kk] = Wo[(kbase + kk) * HID + j];
    }
    asm volatile("" ::: "memory");   // forbid remat of the weight loads

    if (tid < 144) { h_pad[tid] = 0.f; rh_pad[tid] = 0.f; }

    float hj = 0.f;                    // this j's state (replicated over q)
    const float* __restrict__ xg0 = XG + ((size_t)b * SEQ) * 384;
    float xr = xg0[j], xu = xg0[128 + j], xo = xg0[256 + j];
    __syncthreads();

    const int qbase = q * 16 + 4 * (q >> 1);   // padded word offset of this K-chunk

    for (int t = 0; t < SEQ; ++t) {
        // prefetch xg for t+1 (clamped) — consumed next iteration
        const int tn = (t + 1 < SEQ) ? t + 1 : t;
        const float* __restrict__ xgn = XG + ((size_t)b * SEQ + tn) * 384;
        float nr = xgn[j], nu = xgn[128 + j], no = xgn[256 + j];

        // ---- phase 1: r,u dot products over this lane's K-eighth (16 k)
        float4 h4[4];
        {
            const float4* hp = (const float4*)(h_pad + qbase);
#pragma unroll
            for (int rr = 0; rr < 4; ++rr) h4[rr] = hp[rr];
        }
        float pr = 0.f, pu = 0.f;
#pragma unroll
        for (int rr = 0; rr < 4; ++rr) {
            float4 v = h4[rr];
            pr += wr[4*rr]*v.x + wr[4*rr+1]*v.y + wr[4*rr+2]*v.z + wr[4*rr+3]*v.w;
            pu += wu[4*rr]*v.x + wu[4*rr+1]*v.y + wu[4*rr+2]*v.z + wu[4*rr+3]*v.w;
        }
        pr += __shfl_xor(pr, 1); pr += __shfl_xor(pr, 2); pr += __shfl_xor(pr, 4);
        pu += __shfl_xor(pu, 1); pu += __shfl_xor(pu, 2); pu += __shfl_xor(pu, 4);

        float rg = fast_sigmoid(pr + xr);
        float ug = fast_sigmoid(pu + xu);
        if (q == 0) rh_pad[PADIDX(j)] = rg * hj;
        __syncthreads();

        // ---- phase 2: o dot product over rh
        float4 r4[4];
        {
            const float4* rp = (const float4*)(rh_pad + qbase);
#pragma unroll
            for (int rr = 0; rr < 4; ++rr) r4[rr] = rp[rr];
        }
        float po = 0.f;
#pragma unroll
        for (int rr = 0; rr < 4; ++rr) {
            float4 v = r4[rr];
            po += wo[4*rr]*v.x + wo[4*rr+1]*v.y + wo[4*rr+2]*v.z + wo[4*rr+3]*v.w;
        }
        po += __shfl_xor(po, 1); po += __shfl_xor(po, 2); po += __shfl_xor(po, 4);

        float og = fast_tanh(po + xo);
        hj = hj + ug * (og - hj);
        if (q == 0) h_pad[PADIDX(j)] = hj;
        if (LAYER == 0) {
            if (q == 1) H0bf[((size_t)b * SEQ + t) * HID + j] = f2bf(hj);
        }
        xr = nr; xu = nu; xo = no;
        __syncthreads();
    }

    if (LAYER == 1) {
        // publish final h1 densely, then fused classifier (2 cols/thread)
        if (q == 0) h_fin[j] = hj;
        __syncthreads();

        const int c0  = tid;
        const int c1t = tid + 1024;
        const int c1  = (c1t < NCLS) ? c1t : 0;
        float a0 = bfc[c0], a1 = bfc[c1];
#pragma unroll 4
        for (int k = 0; k < HID; ++k) {
            float hk = h_fin[k];
            const float* __restrict__ wrow = Wfc + (size_t)k * NCLS;
            a0 += hk * wrow[c0];
            a1 += hk * wrow[c1];
        }
        float* orow = out + (size_t)b * NCLS;
        orow[c0] = a0;
        if (c1t < NCLS) orow[c1t] = a1;
    }
}

// ---------------------------------------------------------------------------
extern "C" void kernel_launch(void* const* d_in, const int* in_sizes, int n_in,
                              void* d_out, int out_size, void* d_ws, size_t ws_size,
                              hipStream_t stream)
{
    const float* X   = (const float*)d_in[0];
    const float* Wr0 = (const float*)d_in[1];
    const float* br0 = (const float*)d_in[2];
    const float* Wu0 = (const float*)d_in[3];
    const float* bu0 = (const float*)d_in[4];
    const float* Wo0 = (const float*)d_in[5];
    const float* bo0 = (const float*)d_in[6];
    const float* Wr1 = (const float*)d_in[7];
    const float* br1 = (const float*)d_in[8];
    const float* Wu1 = (const float*)d_in[9];
    const float* bu1 = (const float*)d_in[10];
    const float* Wo1 = (const float*)d_in[11];
    const float* bo1 = (const float*)d_in[12];
    const float* Wfc = (const float*)d_in[13];
    const float* bfc = (const float*)d_in[14];
    float* out = (float*)d_out;

    char* ws = (char*)d_ws;
    float*          XG   = (float*)ws;                                         // 110.5 MB
    unsigned short* Abf  = (unsigned short*)(ws + (size_t)M_TOT * 384 * 4);    //  41.4 MB
    unsigned short* H0bf = Abf;   // reuse: Abf dead once gemm l0 completes
    unsigned short* Wt0  = (unsigned short*)(ws + (size_t)M_TOT * 384 * 4 + (size_t)M_TOT * KPAD0 * 2);
    unsigned short* Wt1  = Wt0 + (size_t)3 * HID * KPAD0;

    wt_kernel<<<dim3(6, 32), 256, 0, stream>>>(Wr0, Wu0, Wo0, Wr1, Wu1, Wo1, Wt0, Wt1);
    xt_kernel<<<dim3(5, BATCH), 256, 0, stream>>>(X, Abf);
    gemm_xg  <<<dim3(M_TOT / 128, 3), 256, 0, stream>>>(Abf, Wt0, br0, bu0, bo0, XG, KPAD0);
    gru_rec<0><<<dim3(BATCH), 1024, 0, stream>>>(Wr0, Wu0, Wo0, XG, H0bf, nullptr, nullptr, nullptr);
    gemm_xg  <<<dim3(M_TOT / 128, 3), 256, 0, stream>>>(H0bf, Wt1, br1, bu1, bo1, XG, KPAD1);
    gru_rec<1><<<dim3(BATCH), 1024, 0, stream>>>(Wr1, Wu1, Wo1, XG, nullptr, Wfc, bfc, out);
}